// Round 4
// baseline (311.976 us; speedup 1.0000x reference)
//
#include <hip/hip_runtime.h>

// Dims (from reference): N=100000, E=1600000, D=8, K=1, F=32 everywhere.
#define F 32
#define D 8
#define BKN 256     // nodes per bucket (391 buckets -> csr fills all 256 CUs)
#define BKSH 8      // log2(BKN)
#define EPT 8       // edges per thread in bin path (512 thr * 8 = 4096/block)
#define CAP 4608    // fixed bucket capacity (mean 4096, sd ~64 -> +8 sigma)

typedef unsigned uv2 __attribute__((ext_vector_type(2)));
typedef float fv2 __attribute__((ext_vector_type(2)));
typedef float fv4 __attribute__((ext_vector_type(4)));

__device__ __forceinline__ unsigned f2bf(float f) {      // fp32 -> bf16 bits (RNE)
    unsigned u = __float_as_uint(f);
    return (u + 0x7fffu + ((u >> 16) & 1u)) >> 16;
}
__device__ __forceinline__ float bf2f(unsigned b) {      // bf16 bits (low 16) -> fp32
    return __uint_as_float(b << 16);
}

// ---------------- fused: [0,binBlocks) bin edges ; rest: layer-1 transform ----------------
__global__ void build_kernel(const int* __restrict__ ei, const float* __restrict__ ew,
                             const float* __restrict__ mu1, const float* __restrict__ sg1,
                             const float* __restrict__ mu2, const float* __restrict__ sg2,
                             int* __restrict__ bcur, uv2* __restrict__ bin, int NB, int E,
                             const float* __restrict__ x, const float* __restrict__ g1,
                             const float* __restrict__ root1, const float* __restrict__ b1,
                             unsigned short* __restrict__ xgh, float* __restrict__ xr,
                             int N, int binBlocks) {
    __shared__ int hist[512];
    __shared__ int cbase[512];
    __shared__ float gs[F * F];
    __shared__ float rs[F * F];
    int t = threadIdx.x;

    if ((int)blockIdx.x < binBlocks) {
        // ---- bin path ----
        float m1v[D], i1[D], m2v[D], i2[D];
#pragma unroll
        for (int d = 0; d < D; ++d) {
            m1v[d] = mu1[d];
            i1[d] = -0.5f / (1e-15f + sg1[d] * sg1[d]);
            m2v[d] = mu2[d];
            i2[d] = -0.5f / (1e-15f + sg2[d] * sg2[d]);
        }
        if (t < NB) hist[t] = 0;
        __syncthreads();
        int e0 = blockIdx.x * (512 * EPT) + t;
        unsigned pks[EPT], gps[EPT];
        int bks[EPT];
#pragma unroll
        for (int k = 0; k < EPT; ++k) {
            int e = e0 + k * 512;
            bks[k] = -1;
            if (e < E) {
                int src = __builtin_nontemporal_load(&ei[e]);
                int dst = __builtin_nontemporal_load(&ei[E + e]);
                bks[k] = dst >> BKSH;
                pks[k] = (unsigned)src | ((unsigned)(dst & (BKN - 1)) << 20);
                const fv4* ew4 = (const fv4*)(ew + (size_t)e * D);
                fv4 w0 = __builtin_nontemporal_load(ew4);
                fv4 w1 = __builtin_nontemporal_load(ew4 + 1);
                float w[D] = {w0.x, w0.y, w0.z, w0.w, w1.x, w1.y, w1.z, w1.w};
                float s1 = 0.f, s2 = 0.f;
#pragma unroll
                for (int d = 0; d < D; ++d) {
                    float d1 = w[d] - m1v[d];
                    s1 += d1 * d1 * i1[d];
                    float d2 = w[d] - m2v[d];
                    s2 += d2 * d2 * i2[d];
                }
                gps[k] = f2bf(expf(s1)) | (f2bf(expf(s2)) << 16);
                atomicAdd(&hist[bks[k]], 1);
            }
        }
        __syncthreads();
        if (t < NB) {
            int c = hist[t];
            cbase[t] = t * CAP + (c ? atomicAdd(&bcur[t], c) : 0);
        }
        __syncthreads();
        if (t < NB) hist[t] = 0;                 // reuse as local cursor
        __syncthreads();
#pragma unroll
        for (int k = 0; k < EPT; ++k) {
            if (bks[k] >= 0) {
                int pos = cbase[bks[k]] + atomicAdd(&hist[bks[k]], 1);
                if (pos < (bks[k] + 1) * CAP) {  // overflow guard (statistically never)
                    uv2 p;
                    p.x = pks[k];
                    p.y = gps[k];
                    bin[pos] = p;                // PLAIN store: let L2 write-combine
                }
            }
        }
    } else {
        // ---- transform path: xgh = bf16(x@g1) ; xr = x@root1 + b1 ----
        for (int i = t; i < F * F; i += 512) {
            gs[i] = g1[i];
            rs[i] = root1[i];
        }
        __syncthreads();
        int m = t & 31;
        int node = (int)((((size_t)blockIdx.x - binBlocks) * 512 + t) >> 5);
        if (node >= N) return;
        float xv = x[(size_t)node * F + m];
        int base = t & 32;
        float accg = 0.f, accr = 0.f;
#pragma unroll
        for (int c = 0; c < F; ++c) {
            float xc = __shfl(xv, base + c, 64);
            accg += xc * gs[c * F + m];
            accr += xc * rs[c * F + m];
        }
        xgh[(size_t)node * F + m] = (unsigned short)f2bf(accg);
        xr[(size_t)node * F + m] = accr + b1[m];
    }
}

// ---------------- per-bucket CSR build + compact payload (1024 threads) ----------------
__global__ void csr_kernel(const uv2* __restrict__ bin, const int* __restrict__ bcur,
                           int2* __restrict__ off2, uv2* __restrict__ edata, int N) {
    int b = blockIdx.x;
    int ebase = b * CAP;
    int nE = min(bcur[b], CAP);
    __shared__ int cnt[BKN];
    __shared__ int cur[BKN];
    __shared__ int ps[BKN];
    int t = threadIdx.x;
    if (t < BKN) cnt[t] = 0;
    __syncthreads();
    for (int i = t; i < nE; i += 1024)
        atomicAdd(&cnt[(bin[ebase + i].x >> 20) & (BKN - 1)], 1);
    __syncthreads();
    int a = (t < BKN) ? cnt[t] : 0;
    if (t < BKN) ps[t] = a;
    __syncthreads();
    for (int d = 1; d < BKN; d <<= 1) {
        int u = (t < BKN && t >= d) ? ps[t - d] : 0;
        __syncthreads();
        if (t < BKN) ps[t] += u;
        __syncthreads();
    }
    if (t < BKN) {
        int excl = ps[t] - a;
        cur[t] = excl;
        int node = (b << BKSH) + t;
        if (node < N) {
            int2 o;
            o.x = ebase + excl;
            o.y = ebase + excl + a;
            off2[node] = o;
        }
    }
    __syncthreads();
    for (int i = t; i < nE; i += 1024) {
        uv2 p = bin[ebase + i];
        int dl = (p.x >> 20) & (BKN - 1);
        int pos = ebase + atomicAdd(&cur[dl], 1);
        uv2 q;
        q.x = p.x & 0xfffffu;                     // src only
        q.y = p.y;
        edata[pos] = q;
    }
}

// ---------------- layer-1 aggregate + FUSED layer-2 transform ----------------
// Two nodes per 16-lane group: both 16-deep gather batches are issued before any
// FMA consumes them -> 128 edge-lines in flight per wave (MLP x2 vs one node).
// OOB lanes carry pk=0/gv=0 so the shuffled s=0 gather is safe (L1-hit line 0).
__global__ void agg1_fuse_kernel(const int2* __restrict__ off2,
                                 const uv2* __restrict__ edata,
                                 const unsigned* __restrict__ xg32,
                                 const fv2* __restrict__ xr2,
                                 const float* __restrict__ g2,
                                 const float* __restrict__ root2,
                                 const float* __restrict__ b2,
                                 unsigned* __restrict__ xg32_out,
                                 float2* __restrict__ xr2_out,
                                 int N) {
    __shared__ float gs[F * F];
    __shared__ float rs[F * F];
    for (int i = threadIdx.x; i < F * F; i += blockDim.x) {
        gs[i] = g2[i];
        rs[i] = root2[i];
    }
    __syncthreads();
    int t = threadIdx.x;
    int l = t & 15;
    int grp = (int)((blockIdx.x * (size_t)blockDim.x + t) >> 4);
    int nA = 2 * grp, nB = 2 * grp + 1;
    if (nA >= N) return;
    bool hB = nB < N;
    int base = t & 48;
    int2 soA = off2[nA];
    int2 soB = hB ? off2[nB] : soA;
    if (!hB) { soB.y = soB.x; }
    int sA0 = soA.x, sA1 = soA.y, sB0 = soB.x, sB1 = soB.y;
    int degA = sA1 - sA0, degB = sB1 - sB0;
    float a0A = 0.f, a1A = 0.f, a0B = 0.f, a1B = 0.f;
    int iA = sA0, iB = sB0;
    while (iA < sA1 || iB < sB1) {
        unsigned pkA = 0, pkB = 0;
        float gvA = 0.f, gvB = 0.f;
        if (iA + l < sA1) {
            uv2 ed = edata[iA + l];               // plain load: agg2 re-reads edata
            pkA = ed.x;
            gvA = bf2f(ed.y & 0xffffu);
        }
        if (iB + l < sB1) {
            uv2 ed = edata[iB + l];
            pkB = ed.x;
            gvB = bf2f(ed.y & 0xffffu);
        }
        unsigned xvA[16], xvB[16];
        float gjA[16], gjB[16];
#pragma unroll
        for (int j = 0; j < 16; ++j) {
            unsigned s = __shfl(pkA, base + j, 64);
            gjA[j] = __shfl(gvA, base + j, 64);
            xvA[j] = xg32[s * 16 + l];            // 16 A-gathers in flight
        }
#pragma unroll
        for (int j = 0; j < 16; ++j) {
            unsigned s = __shfl(pkB, base + j, 64);
            gjB[j] = __shfl(gvB, base + j, 64);
            xvB[j] = xg32[s * 16 + l];            // +16 B-gathers in flight
        }
#pragma unroll
        for (int j = 0; j < 16; ++j) {
            a0A += bf2f(xvA[j] & 0xffffu) * gjA[j];
            a1A += __uint_as_float(xvA[j] & 0xffff0000u) * gjA[j];
        }
#pragma unroll
        for (int j = 0; j < 16; ++j) {
            a0B += bf2f(xvB[j] & 0xffffu) * gjB[j];
            a1B += __uint_as_float(xvB[j] & 0xffff0000u) * gjB[j];
        }
        iA += 16;
        iB += 16;
    }
    float invA = (degA > 0) ? 1.f / (float)degA : 0.f;
    float invB = (degB > 0) ? 1.f / (float)degB : 0.f;
    fv2 rA = __builtin_nontemporal_load(&xr2[(size_t)nA * 16 + l]);
    float hxA = a0A * invA + rA.x;
    float hyA = a1A * invA + rA.y;
    float hxB = 0.f, hyB = 0.f;
    if (hB) {
        fv2 rB = __builtin_nontemporal_load(&xr2[(size_t)nB * 16 + l]);
        hxB = a0B * invB + rB.x;
        hyB = a1B * invB + rB.y;
    }
    // ---- fused transform: hg = h@g2 ; hr = h@root2 + b2 (both nodes) ----
    float ag0A = 0.f, ag1A = 0.f, ar0A = 0.f, ar1A = 0.f;
    float ag0B = 0.f, ag1B = 0.f, ar0B = 0.f, ar1B = 0.f;
#pragma unroll
    for (int c = 0; c < F; ++c) {
        float g0 = gs[c * F + 2 * l], g1v = gs[c * F + 2 * l + 1];
        float r0 = rs[c * F + 2 * l], r1v = rs[c * F + 2 * l + 1];
        float srcA = (c & 1) ? hyA : hxA;
        float hcA = __shfl(srcA, base + (c >> 1), 64);
        ag0A += hcA * g0;
        ag1A += hcA * g1v;
        ar0A += hcA * r0;
        ar1A += hcA * r1v;
        float srcB = (c & 1) ? hyB : hxB;
        float hcB = __shfl(srcB, base + (c >> 1), 64);
        ag0B += hcB * g0;
        ag1B += hcB * g1v;
        ar0B += hcB * r0;
        ar1B += hcB * r1v;
    }
    float bx = b2[2 * l], by = b2[2 * l + 1];
    xg32_out[(size_t)nA * 16 + l] = f2bf(ag0A) | (f2bf(ag1A) << 16);
    float2 xoA;
    xoA.x = ar0A + bx;
    xoA.y = ar1A + by;
    xr2_out[(size_t)nA * 16 + l] = xoA;
    if (hB) {
        xg32_out[(size_t)nB * 16 + l] = f2bf(ag0B) | (f2bf(ag1B) << 16);
        float2 xoB;
        xoB.x = ar0B + bx;
        xoB.y = ar1B + by;
        xr2_out[(size_t)nB * 16 + l] = xoB;
    }
}

// ---------------- layer-2 aggregate + finalize (writes d_out) ----------------
__global__ void aggregate2_kernel(const int2* __restrict__ off2,
                                  const uv2* __restrict__ edata,
                                  const unsigned* __restrict__ xg32,
                                  const fv2* __restrict__ xr2,
                                  fv2* __restrict__ out2, int N) {
    int t = threadIdx.x;
    int l = t & 15;
    int grp = (int)((blockIdx.x * (size_t)blockDim.x + t) >> 4);
    int nA = 2 * grp, nB = 2 * grp + 1;
    if (nA >= N) return;
    bool hB = nB < N;
    int base = t & 48;
    int2 soA = off2[nA];
    int2 soB = hB ? off2[nB] : soA;
    if (!hB) { soB.y = soB.x; }
    int sA0 = soA.x, sA1 = soA.y, sB0 = soB.x, sB1 = soB.y;
    int degA = sA1 - sA0, degB = sB1 - sB0;
    float a0A = 0.f, a1A = 0.f, a0B = 0.f, a1B = 0.f;
    int iA = sA0, iB = sB0;
    while (iA < sA1 || iB < sB1) {
        unsigned pkA = 0, pkB = 0;
        float gvA = 0.f, gvB = 0.f;
        if (iA + l < sA1) {
            uv2 ed = __builtin_nontemporal_load(&edata[iA + l]);  // last use of edata
            pkA = ed.x;
            gvA = __uint_as_float(ed.y & 0xffff0000u);
        }
        if (iB + l < sB1) {
            uv2 ed = __builtin_nontemporal_load(&edata[iB + l]);
            pkB = ed.x;
            gvB = __uint_as_float(ed.y & 0xffff0000u);
        }
        unsigned xvA[16], xvB[16];
        float gjA[16], gjB[16];
#pragma unroll
        for (int j = 0; j < 16; ++j) {
            unsigned s = __shfl(pkA, base + j, 64);
            gjA[j] = __shfl(gvA, base + j, 64);
            xvA[j] = xg32[s * 16 + l];
        }
#pragma unroll
        for (int j = 0; j < 16; ++j) {
            unsigned s = __shfl(pkB, base + j, 64);
            gjB[j] = __shfl(gvB, base + j, 64);
            xvB[j] = xg32[s * 16 + l];
        }
#pragma unroll
        for (int j = 0; j < 16; ++j) {
            a0A += bf2f(xvA[j] & 0xffffu) * gjA[j];
            a1A += __uint_as_float(xvA[j] & 0xffff0000u) * gjA[j];
        }
#pragma unroll
        for (int j = 0; j < 16; ++j) {
            a0B += bf2f(xvB[j] & 0xffffu) * gjB[j];
            a1B += __uint_as_float(xvB[j] & 0xffff0000u) * gjB[j];
        }
        iA += 16;
        iB += 16;
    }
    float invA = (degA > 0) ? 1.f / (float)degA : 0.f;
    float invB = (degB > 0) ? 1.f / (float)degB : 0.f;
    fv2 rA = __builtin_nontemporal_load(&xr2[(size_t)nA * 16 + l]);
    fv2 oA;
    oA.x = a0A * invA + rA.x;
    oA.y = a1A * invA + rA.y;
    __builtin_nontemporal_store(oA, &out2[(size_t)nA * 16 + l]);
    if (hB) {
        fv2 rB = __builtin_nontemporal_load(&xr2[(size_t)nB * 16 + l]);
        fv2 oB;
        oB.x = a0B * invB + rB.x;
        oB.y = a1B * invB + rB.y;
        __builtin_nontemporal_store(oB, &out2[(size_t)nB * 16 + l]);
    }
}

extern "C" void kernel_launch(void* const* d_in, const int* in_sizes, int n_in,
                              void* d_out, int out_size, void* d_ws, size_t ws_size,
                              hipStream_t stream) {
    const int*   ei   = (const int*)d_in[0];     // (2, E) int32
    const float* ew   = (const float*)d_in[1];   // (E, 8)
    const float* x    = (const float*)d_in[2];   // (N, 32)
    const float* g1   = (const float*)d_in[3];
    const float* mu1  = (const float*)d_in[4];
    const float* sg1  = (const float*)d_in[5];
    const float* r1   = (const float*)d_in[6];
    const float* b1   = (const float*)d_in[7];
    const float* g2   = (const float*)d_in[8];
    const float* mu2  = (const float*)d_in[9];
    const float* sg2  = (const float*)d_in[10];
    const float* r2   = (const float*)d_in[11];
    const float* b2   = (const float*)d_in[12];
    float* out = (float*)d_out;

    const int E = in_sizes[0] / 2;
    const int N = in_sizes[2] / F;
    const size_t NF = (size_t)N * F;
    const int NB = (N + BKN - 1) / BKN;          // 391 buckets for N=100000

    // workspace layout
    uv2*            bin   = (uv2*)d_ws;                   // NB*CAP * 8B (~14.4 MB)
    uv2*            edata = bin + (size_t)NB * CAP;       // NB*CAP * 8B
    float*          xr1   = (float*)(edata + (size_t)NB * CAP); // NF * 4B
    float*          xr2w  = xr1 + NF;                     // NF * 4B
    unsigned short* xgh1  = (unsigned short*)(xr2w + NF); // NF * 2B
    unsigned short* xgh2  = xgh1 + NF;                    // NF * 2B
    int2*           off2  = (int2*)(xgh2 + NF);           // N * 8B
    int*            bcur  = (int*)(off2 + N);             // NB

    const int BT = 256;
    const int blk_bin = (E + 512 * EPT - 1) / (512 * EPT);            // 391
    const int blk_tr  = (int)((NF + 511) / 512);                      // 6250
    const int nGrp    = (N + 1) / 2;                                  // 2 nodes per group
    const int blk_agg = (int)(((size_t)nGrp * 16 + BT - 1) / BT);     // 3125

    (void)hipMemsetAsync(bcur, 0, NB * sizeof(int), stream);

    // ---- fused bin + layer-1 transform ----
    build_kernel<<<blk_bin + blk_tr, 512, 0, stream>>>(
        ei, ew, mu1, sg1, mu2, sg2, bcur, bin, NB, E,
        x, g1, r1, b1, xgh1, xr1, N, blk_bin);

    // ---- per-bucket CSR ----
    csr_kernel<<<NB, 1024, 0, stream>>>(bin, bcur, off2, edata, N);

    // ---- layer-1 aggregate + fused layer-2 transform ----
    agg1_fuse_kernel<<<blk_agg, BT, 0, stream>>>(off2, edata, (const unsigned*)xgh1,
                                                 (const fv2*)xr1, g2, r2, b2,
                                                 (unsigned*)xgh2, (float2*)xr2w, N);

    // ---- layer-2 aggregate -> out ----
    aggregate2_kernel<<<blk_agg, BT, 0, stream>>>(off2, edata, (const unsigned*)xgh2,
                                                  (const fv2*)xr2w, (fv2*)out, N);
}

// Round 6
// 239.563 us; speedup vs baseline: 1.3023x; 1.3023x over previous
//
#include <hip/hip_runtime.h>

// Dims (from reference): N=100000, E=1600000, D=8, K=1, F=32 everywhere.
#define F 32
#define D 8
#define BKN 256     // nodes per bucket (391 buckets -> csr/agg fill all 256 CUs)
#define BKSH 8      // log2(BKN)
#define EPT 8       // edges per thread in bin path (512 thr * 8 = 4096/block)
#define CAP 4608    // fixed bucket capacity (mean 4096, sd ~64 -> +8 sigma)

typedef unsigned uv2 __attribute__((ext_vector_type(2)));
typedef float fv2 __attribute__((ext_vector_type(2)));
typedef float fv4 __attribute__((ext_vector_type(4)));

__device__ __forceinline__ unsigned f2bf(float f) {      // fp32 -> bf16 bits (RNE)
    unsigned u = __float_as_uint(f);
    return (u + 0x7fffu + ((u >> 16) & 1u)) >> 16;
}
__device__ __forceinline__ float bf2f(unsigned b) {      // bf16 bits (low 16) -> fp32
    return __uint_as_float(b << 16);
}

// ---------------- fused: [0,binBlocks) bin edges ; rest: layer-1 transform ----------------
__global__ void build_kernel(const int* __restrict__ ei, const float* __restrict__ ew,
                             const float* __restrict__ mu1, const float* __restrict__ sg1,
                             const float* __restrict__ mu2, const float* __restrict__ sg2,
                             int* __restrict__ bcur, uv2* __restrict__ bin, int NB, int E,
                             const float* __restrict__ x, const float* __restrict__ g1,
                             const float* __restrict__ root1, const float* __restrict__ b1,
                             unsigned short* __restrict__ xgh, float* __restrict__ xr,
                             int N, int binBlocks) {
    __shared__ int hist[512];
    __shared__ int cbase[512];
    __shared__ float gs[F * F];
    __shared__ float rs[F * F];
    int t = threadIdx.x;

    if ((int)blockIdx.x < binBlocks) {
        // ---- bin path ----
        float m1v[D], i1[D], m2v[D], i2[D];
#pragma unroll
        for (int d = 0; d < D; ++d) {
            m1v[d] = mu1[d];
            i1[d] = -0.5f / (1e-15f + sg1[d] * sg1[d]);
            m2v[d] = mu2[d];
            i2[d] = -0.5f / (1e-15f + sg2[d] * sg2[d]);
        }
        if (t < NB) hist[t] = 0;
        __syncthreads();
        int e0 = blockIdx.x * (512 * EPT) + t;
        unsigned pks[EPT], gps[EPT];
        int bks[EPT];
#pragma unroll
        for (int k = 0; k < EPT; ++k) {
            int e = e0 + k * 512;
            bks[k] = -1;
            if (e < E) {
                int src = __builtin_nontemporal_load(&ei[e]);
                int dst = __builtin_nontemporal_load(&ei[E + e]);
                bks[k] = dst >> BKSH;
                pks[k] = (unsigned)src | ((unsigned)(dst & (BKN - 1)) << 20);
                const fv4* ew4 = (const fv4*)(ew + (size_t)e * D);
                fv4 w0 = __builtin_nontemporal_load(ew4);
                fv4 w1 = __builtin_nontemporal_load(ew4 + 1);
                float w[D] = {w0.x, w0.y, w0.z, w0.w, w1.x, w1.y, w1.z, w1.w};
                float s1 = 0.f, s2 = 0.f;
#pragma unroll
                for (int d = 0; d < D; ++d) {
                    float d1 = w[d] - m1v[d];
                    s1 += d1 * d1 * i1[d];
                    float d2 = w[d] - m2v[d];
                    s2 += d2 * d2 * i2[d];
                }
                gps[k] = f2bf(expf(s1)) | (f2bf(expf(s2)) << 16);
                atomicAdd(&hist[bks[k]], 1);
            }
        }
        __syncthreads();
        if (t < NB) {
            int c = hist[t];
            cbase[t] = t * CAP + (c ? atomicAdd(&bcur[t], c) : 0);
        }
        __syncthreads();
        if (t < NB) hist[t] = 0;                 // reuse as local cursor
        __syncthreads();
#pragma unroll
        for (int k = 0; k < EPT; ++k) {
            if (bks[k] >= 0) {
                int pos = cbase[bks[k]] + atomicAdd(&hist[bks[k]], 1);
                if (pos < (bks[k] + 1) * CAP) {  // overflow guard (statistically never)
                    uv2 p;
                    p.x = pks[k];
                    p.y = gps[k];
                    bin[pos] = p;                // PLAIN store: let L2 write-combine
                }
            }
        }
    } else {
        // ---- transform path: xgh = bf16(x@g1) ; xr = x@root1 + b1 ----
        for (int i = t; i < F * F; i += 512) {
            gs[i] = g1[i];
            rs[i] = root1[i];
        }
        __syncthreads();
        int m = t & 31;
        int node = (int)((((size_t)blockIdx.x - binBlocks) * 512 + t) >> 5);
        if (node >= N) return;
        float xv = x[(size_t)node * F + m];
        int base = t & 32;
        float accg = 0.f, accr = 0.f;
#pragma unroll
        for (int c = 0; c < F; ++c) {
            float xc = __shfl(xv, base + c, 64);
            accg += xc * gs[c * F + m];
            accr += xc * rs[c * F + m];
        }
        xgh[(size_t)node * F + m] = (unsigned short)f2bf(accg);
        xr[(size_t)node * F + m] = accr + b1[m];
    }
}

// ---------------- per-bucket CSR build + compact payload (1024 threads) ----------------
__global__ void csr_kernel(const uv2* __restrict__ bin, const int* __restrict__ bcur,
                           int2* __restrict__ off2, uv2* __restrict__ edata, int N) {
    int b = blockIdx.x;
    int ebase = b * CAP;
    int nE = min(bcur[b], CAP);
    __shared__ int cnt[BKN];
    __shared__ int cur[BKN];
    __shared__ int ps[BKN];
    int t = threadIdx.x;
    if (t < BKN) cnt[t] = 0;
    __syncthreads();
    for (int i = t; i < nE; i += 1024)
        atomicAdd(&cnt[(bin[ebase + i].x >> 20) & (BKN - 1)], 1);
    __syncthreads();
    int a = (t < BKN) ? cnt[t] : 0;
    if (t < BKN) ps[t] = a;
    __syncthreads();
    for (int d = 1; d < BKN; d <<= 1) {
        int u = (t < BKN && t >= d) ? ps[t - d] : 0;
        __syncthreads();
        if (t < BKN) ps[t] += u;
        __syncthreads();
    }
    if (t < BKN) {
        int excl = ps[t] - a;
        cur[t] = excl;
        int node = (b << BKSH) + t;
        if (node < N) {
            int2 o;
            o.x = ebase + excl;
            o.y = ebase + excl + a;
            off2[node] = o;
        }
    }
    __syncthreads();
    for (int i = t; i < nE; i += 1024) {
        uv2 p = bin[ebase + i];
        int dl = (p.x >> 20) & (BKN - 1);
        int pos = ebase + atomicAdd(&cur[dl], 1);
        uv2 q;
        q.x = p.x & 0xfffffu;                     // src only
        q.y = p.y;
        edata[pos] = q;
    }
}

// ---------------- layer-1 aggregate + FUSED layer-2 transform ----------------
// Inner loop is branch-free: edata load is clamped in-bounds and pk/gv are
// predicated by cndmask (OOB lanes contribute 0 via g=0; shuffled s=0 gather
// is an L1-hit). All 16 gathers issued before any FMA consumes them.
__global__ void agg1_fuse_kernel(const int2* __restrict__ off2,
                                 const uv2* __restrict__ edata,
                                 const unsigned* __restrict__ xg32,
                                 const fv2* __restrict__ xr2,
                                 const float* __restrict__ g2,
                                 const float* __restrict__ root2,
                                 const float* __restrict__ b2,
                                 unsigned* __restrict__ xg32_out,
                                 fv2* __restrict__ xr2_out,
                                 int N) {
    __shared__ float gs[F * F];
    __shared__ float rs[F * F];
    for (int i = threadIdx.x; i < F * F; i += blockDim.x) {
        gs[i] = g2[i];
        rs[i] = root2[i];
    }
    __syncthreads();
    int t = threadIdx.x;
    int l = t & 15;
    int node = (int)((blockIdx.x * (size_t)blockDim.x + t) >> 4);
    if (node >= N) return;
    int base = t & 48;
    int2 so = off2[node];
    int s0 = so.x, s1 = so.y;
    int deg = s1 - s0;
    float a0 = 0.f, a1 = 0.f;
    for (int i = s0; i < s1; i += 16) {
        uv2 ed = __builtin_nontemporal_load(&edata[min(i + l, s1 - 1)]);
        bool ok = (i + l < s1);
        unsigned pk = ok ? ed.x : 0u;
        float gv = ok ? bf2f(ed.y & 0xffffu) : 0.f;
        unsigned xv[16];
        float gj[16];
#pragma unroll
        for (int j = 0; j < 16; ++j) {
            unsigned s = __shfl(pk, base + j, 64);
            gj[j] = __shfl(gv, base + j, 64);
            xv[j] = xg32[s * 16 + l];             // issued with no consumer: 16 in flight
        }
#pragma unroll
        for (int j = 0; j < 16; ++j) {
            a0 += bf2f(xv[j] & 0xffffu) * gj[j];
            a1 += __uint_as_float(xv[j] & 0xffff0000u) * gj[j];
        }
    }
    float inv = (deg > 0) ? 1.f / (float)deg : 0.f;
    fv2 r = __builtin_nontemporal_load(&xr2[(size_t)node * 16 + l]);
    float hx = a0 * inv + r.x;
    float hy = a1 * inv + r.y;
    // ---- fused transform: hg = h@g2 ; hr = h@root2 + b2 ----
    float ag0 = 0.f, ag1 = 0.f, ar0 = 0.f, ar1 = 0.f;
#pragma unroll
    for (int c = 0; c < F; ++c) {
        float src = (c & 1) ? hy : hx;
        float hc = __shfl(src, base + (c >> 1), 64);
        ag0 += hc * gs[c * F + 2 * l];
        ag1 += hc * gs[c * F + 2 * l + 1];
        ar0 += hc * rs[c * F + 2 * l];
        ar1 += hc * rs[c * F + 2 * l + 1];
    }
    unsigned og = f2bf(ag0) | (f2bf(ag1) << 16);
    __builtin_nontemporal_store(og, &xg32_out[(size_t)node * 16 + l]);
    fv2 xo;
    xo.x = ar0 + b2[2 * l];
    xo.y = ar1 + b2[2 * l + 1];
    __builtin_nontemporal_store(xo, &xr2_out[(size_t)node * 16 + l]);
}

// ---------------- layer-2 aggregate + finalize (writes d_out) ----------------
__global__ void aggregate2_kernel(const int2* __restrict__ off2,
                                  const uv2* __restrict__ edata,
                                  const unsigned* __restrict__ xg32,
                                  const fv2* __restrict__ xr2,
                                  fv2* __restrict__ out2, int N) {
    int t = threadIdx.x;
    int l = t & 15;
    int node = (int)((blockIdx.x * (size_t)blockDim.x + t) >> 4);
    if (node >= N) return;
    int base = t & 48;
    int2 so = off2[node];
    int s0 = so.x, s1 = so.y;
    int deg = s1 - s0;
    float a0 = 0.f, a1 = 0.f;
    for (int i = s0; i < s1; i += 16) {
        uv2 ed = __builtin_nontemporal_load(&edata[min(i + l, s1 - 1)]);
        bool ok = (i + l < s1);
        unsigned pk = ok ? ed.x : 0u;
        float gv = ok ? __uint_as_float(ed.y & 0xffff0000u) : 0.f;
        unsigned xv[16];
        float gj[16];
#pragma unroll
        for (int j = 0; j < 16; ++j) {
            unsigned s = __shfl(pk, base + j, 64);
            gj[j] = __shfl(gv, base + j, 64);
            xv[j] = xg32[s * 16 + l];
        }
#pragma unroll
        for (int j = 0; j < 16; ++j) {
            a0 += bf2f(xv[j] & 0xffffu) * gj[j];
            a1 += __uint_as_float(xv[j] & 0xffff0000u) * gj[j];
        }
    }
    float inv = (deg > 0) ? 1.f / (float)deg : 0.f;
    fv2 r = __builtin_nontemporal_load(&xr2[(size_t)node * 16 + l]);
    fv2 o;
    o.x = a0 * inv + r.x;
    o.y = a1 * inv + r.y;
    __builtin_nontemporal_store(o, &out2[(size_t)node * 16 + l]);
}

extern "C" void kernel_launch(void* const* d_in, const int* in_sizes, int n_in,
                              void* d_out, int out_size, void* d_ws, size_t ws_size,
                              hipStream_t stream) {
    const int*   ei   = (const int*)d_in[0];     // (2, E) int32
    const float* ew   = (const float*)d_in[1];   // (E, 8)
    const float* x    = (const float*)d_in[2];   // (N, 32)
    const float* g1   = (const float*)d_in[3];
    const float* mu1  = (const float*)d_in[4];
    const float* sg1  = (const float*)d_in[5];
    const float* r1   = (const float*)d_in[6];
    const float* b1   = (const float*)d_in[7];
    const float* g2   = (const float*)d_in[8];
    const float* mu2  = (const float*)d_in[9];
    const float* sg2  = (const float*)d_in[10];
    const float* r2   = (const float*)d_in[11];
    const float* b2   = (const float*)d_in[12];
    float* out = (float*)d_out;

    const int E = in_sizes[0] / 2;
    const int N = in_sizes[2] / F;
    const size_t NF = (size_t)N * F;
    const int NB = (N + BKN - 1) / BKN;          // 391 buckets for N=100000

    // workspace layout
    uv2*            bin   = (uv2*)d_ws;                   // NB*CAP * 8B (~14.4 MB)
    uv2*            edata = bin + (size_t)NB * CAP;       // NB*CAP * 8B
    float*          xr1   = (float*)(edata + (size_t)NB * CAP); // NF * 4B
    float*          xr2w  = xr1 + NF;                     // NF * 4B
    unsigned short* xgh1  = (unsigned short*)(xr2w + NF); // NF * 2B
    unsigned short* xgh2  = xgh1 + NF;                    // NF * 2B
    int2*           off2  = (int2*)(xgh2 + NF);           // N * 8B
    int*            bcur  = (int*)(off2 + N);             // NB

    const int BT = 256;
    const int blk_bin = (E + 512 * EPT - 1) / (512 * EPT);            // 391
    const int blk_tr  = (int)((NF + 511) / 512);                      // 6250
    const int blk_agg = (int)(((size_t)N * 16 + BT - 1) / BT);        // 6250

    (void)hipMemsetAsync(bcur, 0, NB * sizeof(int), stream);

    // ---- fused bin + layer-1 transform ----
    build_kernel<<<blk_bin + blk_tr, 512, 0, stream>>>(
        ei, ew, mu1, sg1, mu2, sg2, bcur, bin, NB, E,
        x, g1, r1, b1, xgh1, xr1, N, blk_bin);

    // ---- per-bucket CSR ----
    csr_kernel<<<NB, 1024, 0, stream>>>(bin, bcur, off2, edata, N);

    // ---- layer-1 aggregate + fused layer-2 transform ----
    agg1_fuse_kernel<<<blk_agg, BT, 0, stream>>>(off2, edata, (const unsigned*)xgh1,
                                                 (const fv2*)xr1, g2, r2, b2,
                                                 (unsigned*)xgh2, (fv2*)xr2w, N);

    // ---- layer-2 aggregate -> out ----
    aggregate2_kernel<<<blk_agg, BT, 0, stream>>>(off2, edata, (const unsigned*)xgh2,
                                                  (const fv2*)xr2w, (fv2*)out, N);
}